// Round 2
// baseline (578.603 us; speedup 1.0000x reference)
//
#include <hip/hip_runtime.h>
#include <cstdint>
#include <cstddef>

// ---------------- problem constants ----------------
#define B_   2
#define T_   2048
#define D_   2048
#define H_   16
#define DH_  128
#define DQ_  1024
#define DKV_ 512
#define DR_  64
#define M_   4096            // B_*T_
#define SCALE_ 0.07216878364870323f   // 1/sqrt(DH_+DR_)
#define SC2_   0.10412808709930322f   // SCALE_ * log2(e)
#define LN_BASE_ 13.122363377404328f  // ln(500000)

typedef unsigned short u16;
typedef __attribute__((ext_vector_type(8))) short short8;   // 8 bf16 (4 VGPRs)
typedef __attribute__((ext_vector_type(4))) float f32x4;    // 4 fp32 acc

__device__ __forceinline__ float b2f(u16 u) { return __uint_as_float(((uint32_t)u) << 16); }
__device__ __forceinline__ u16 f2b(float f) {            // RNE
    uint32_t x = __float_as_uint(f);
    return (u16)((x + 0x7fffu + ((x >> 16) & 1u)) >> 16);
}
__device__ __forceinline__ u16 f2b_fast(float f) {       // round-up-ties, 2 ops
    return (u16)((__float_as_uint(f) + 0x8000u) >> 16);
}

// ---- fused prep: 8 weight transposes (+cast) AND x fp32->bf16, one launch ---
struct TPack {
    const float* src[8];
    u16*         dst[8];
    int K[8];      // src rows
    int N[8];      // src cols (real)
    int ntx[8];    // tiles along out-row dim (covers padded N)
    int start[9];  // cumulative tile offsets
};

__global__ __launch_bounds__(256) void prep_k(TPack p, const float* __restrict__ x,
                                              u16* __restrict__ xb, int ntr) {
    const int bid = blockIdx.x;
    if (bid < ntr) {
        __shared__ float tile[32][33];
        int w = 0;
#pragma unroll
        for (int i = 1; i < 8; ++i) if (bid >= p.start[i]) w = i;
        const int lt = bid - p.start[w];
        const int bx = lt % p.ntx[w], by = lt / p.ntx[w];
        const float* in = p.src[w];
        u16* out = p.dst[w];
        const int K = p.K[w], N = p.N[w];
        const int k0 = by * 32, n0 = bx * 32;
        const int tx = threadIdx.x & 31, ty = threadIdx.x >> 5;  // 32x8
#pragma unroll
        for (int i = 0; i < 4; ++i) {
            int k = k0 + ty + i * 8;
            int n = n0 + tx;
            tile[ty + i * 8][tx] = (n < N) ? in[(size_t)k * N + n] : 0.f;
        }
        __syncthreads();
#pragma unroll
        for (int i = 0; i < 4; ++i) {
            int n = n0 + ty + i * 8;     // out row
            out[(size_t)n * K + k0 + tx] = f2b(tile[tx][ty + i * 8]);
        }
    } else {
        const int i = ((bid - ntr) * 256 + threadIdx.x) * 4;
        const float4 v = *(const float4*)(x + i);
        ushort4 o;
        o.x = f2b(v.x); o.y = f2b(v.y); o.z = f2b(v.z); o.w = f2b(v.w);
        *(ushort4*)(xb + i) = o;
    }
}

// ---------------- bf16 GEMM:  C(MxN) = A(MxK) @ B(KxN), Bt given as NxK ------
template <int OUT_BF16>
__global__ __launch_bounds__(256) void gemm_tn(const u16* __restrict__ A,
                                               const u16* __restrict__ Bt,
                                               void* __restrict__ Cv,
                                               int N, int K) {
    __shared__ __attribute__((aligned(16))) u16 lA[128 * 32];
    __shared__ __attribute__((aligned(16))) u16 lB[128 * 32];
    const int m0 = blockIdx.y * 128, n0 = blockIdx.x * 128;
    const int tid = threadIdx.x, wave = tid >> 6, lane = tid & 63;
    const int wm = (wave >> 1) * 64, wn = (wave & 1) * 64;
    const int r = lane & 15, kq = lane >> 4;

    f32x4 acc[4][4];
#pragma unroll
    for (int i = 0; i < 4; ++i)
#pragma unroll
        for (int j = 0; j < 4; ++j) acc[i][j] = (f32x4){0.f, 0.f, 0.f, 0.f};

    for (int kk = 0; kk < K; kk += 32) {
#pragma unroll
        for (int p = 0; p < 2; ++p) {
            const int c = p * 256 + wave * 64 + lane;          // 16B chunk id
            const u16* ga = A  + (size_t)(m0 + (c >> 2)) * K + kk + (c & 3) * 8;
            const u16* gb = Bt + (size_t)(n0 + (c >> 2)) * K + kk + (c & 3) * 8;
            u16* la = lA + (size_t)(p * 256 + wave * 64) * 8;  // wave-uniform base
            u16* lb = lB + (size_t)(p * 256 + wave * 64) * 8;
            __builtin_amdgcn_global_load_lds(
                (const __attribute__((address_space(1))) uint32_t*)(uintptr_t)ga,
                (__attribute__((address_space(3))) uint32_t*)(uintptr_t)la, 16, 0, 0);
            __builtin_amdgcn_global_load_lds(
                (const __attribute__((address_space(1))) uint32_t*)(uintptr_t)gb,
                (__attribute__((address_space(3))) uint32_t*)(uintptr_t)lb, 16, 0, 0);
        }
        __syncthreads();
        short8 av[4], bv[4];
#pragma unroll
        for (int mi = 0; mi < 4; ++mi)
            av[mi] = *(const short8*)&lA[(wm + mi * 16 + r) * 32 + kq * 8];
#pragma unroll
        for (int ni = 0; ni < 4; ++ni)
            bv[ni] = *(const short8*)&lB[(wn + ni * 16 + r) * 32 + kq * 8];
#pragma unroll
        for (int mi = 0; mi < 4; ++mi)
#pragma unroll
            for (int ni = 0; ni < 4; ++ni)
                acc[mi][ni] = __builtin_amdgcn_mfma_f32_16x16x32_bf16(
                    av[mi], bv[ni], acc[mi][ni], 0, 0, 0);
        __syncthreads();
    }
    const int r4 = (lane >> 4) * 4, cc = lane & 15;
#pragma unroll
    for (int mi = 0; mi < 4; ++mi)
#pragma unroll
        for (int ni = 0; ni < 4; ++ni)
#pragma unroll
            for (int i = 0; i < 4; ++i) {
                const int row = m0 + wm + mi * 16 + r4 + i;
                const int col = n0 + wn + ni * 16 + cc;
                const float v = acc[mi][ni][i];
                if (OUT_BF16) ((u16*)Cv)[(size_t)row * N + col] = f2b(v);
                else          ((float*)Cv)[(size_t)row * N + col] = v;
            }
}

// ---- two bf16 GEMMs in ONE launch (block-range routed): both M=4096 --------
__global__ __launch_bounds__(256) void gemm_pair(const u16* __restrict__ A0,
                                                 const u16* __restrict__ B0,
                                                 u16* __restrict__ C0, int N0, int K0,
                                                 const u16* __restrict__ A1,
                                                 const u16* __restrict__ B1,
                                                 u16* __restrict__ C1, int N1, int K1,
                                                 int nx0) {
    __shared__ __attribute__((aligned(16))) u16 lA[128 * 32];
    __shared__ __attribute__((aligned(16))) u16 lB[128 * 32];
    const int sel = (int)blockIdx.x >= nx0;
    const u16* A  = sel ? A1 : A0;
    const u16* Bt = sel ? B1 : B0;
    u16* Cv = sel ? C1 : C0;
    const int N = sel ? N1 : N0, K = sel ? K1 : K0;
    const int bx = sel ? (blockIdx.x - nx0) : blockIdx.x;
    const int m0 = blockIdx.y * 128, n0 = bx * 128;
    const int tid = threadIdx.x, wave = tid >> 6, lane = tid & 63;
    const int wm = (wave >> 1) * 64, wn = (wave & 1) * 64;
    const int r = lane & 15, kq = lane >> 4;

    f32x4 acc[4][4];
#pragma unroll
    for (int i = 0; i < 4; ++i)
#pragma unroll
        for (int j = 0; j < 4; ++j) acc[i][j] = (f32x4){0.f, 0.f, 0.f, 0.f};

    for (int kk = 0; kk < K; kk += 32) {
#pragma unroll
        for (int p = 0; p < 2; ++p) {
            const int c = p * 256 + wave * 64 + lane;
            const u16* ga = A  + (size_t)(m0 + (c >> 2)) * K + kk + (c & 3) * 8;
            const u16* gb = Bt + (size_t)(n0 + (c >> 2)) * K + kk + (c & 3) * 8;
            u16* la = lA + (size_t)(p * 256 + wave * 64) * 8;
            u16* lb = lB + (size_t)(p * 256 + wave * 64) * 8;
            __builtin_amdgcn_global_load_lds(
                (const __attribute__((address_space(1))) uint32_t*)(uintptr_t)ga,
                (__attribute__((address_space(3))) uint32_t*)(uintptr_t)la, 16, 0, 0);
            __builtin_amdgcn_global_load_lds(
                (const __attribute__((address_space(1))) uint32_t*)(uintptr_t)gb,
                (__attribute__((address_space(3))) uint32_t*)(uintptr_t)lb, 16, 0, 0);
        }
        __syncthreads();
        short8 av[4], bv[4];
#pragma unroll
        for (int mi = 0; mi < 4; ++mi)
            av[mi] = *(const short8*)&lA[(wm + mi * 16 + r) * 32 + kq * 8];
#pragma unroll
        for (int ni = 0; ni < 4; ++ni)
            bv[ni] = *(const short8*)&lB[(wn + ni * 16 + r) * 32 + kq * 8];
#pragma unroll
        for (int mi = 0; mi < 4; ++mi)
#pragma unroll
            for (int ni = 0; ni < 4; ++ni)
                acc[mi][ni] = __builtin_amdgcn_mfma_f32_16x16x32_bf16(
                    av[mi], bv[ni], acc[mi][ni], 0, 0, 0);
        __syncthreads();
    }
    const int r4 = (lane >> 4) * 4, cc = lane & 15;
#pragma unroll
    for (int mi = 0; mi < 4; ++mi)
#pragma unroll
        for (int ni = 0; ni < 4; ++ni)
#pragma unroll
            for (int i = 0; i < 4; ++i) {
                const int row = m0 + wm + mi * 16 + r4 + i;
                const int col = n0 + wn + ni * 16 + cc;
                Cv[(size_t)row * N + col] = f2b(acc[mi][ni][i]);
            }
}

// ---- fused per-row ops on P1: rmsnorm(q), rmsnorm(kv), rope_k — one launch --
__global__ __launch_bounds__(256) void normrope_k(const u16* __restrict__ P1,
                                                  const float* __restrict__ qnw,
                                                  const float* __restrict__ kvnw,
                                                  u16* __restrict__ cQb,
                                                  u16* __restrict__ cKVb,
                                                  u16* __restrict__ kRb) {
    const int row = blockIdx.x;
    const int which = blockIdx.y;
    if (which < 2) {
        const int N = which ? 512 : 1024;
        const int off = which ? 1024 : 0;
        const float* w = which ? kvnw : qnw;
        u16* outp = which ? cKVb : cQb;
        const u16* src = P1 + (size_t)row * 1664 + off;
        const int j = threadIdx.x * 4;
        float v[4] = {0.f, 0.f, 0.f, 0.f};
        if (j < N) {
            ushort4 u = *(const ushort4*)(src + j);
            v[0] = b2f(u.x); v[1] = b2f(u.y); v[2] = b2f(u.z); v[3] = b2f(u.w);
        }
        float ss = v[0]*v[0] + v[1]*v[1] + v[2]*v[2] + v[3]*v[3];
#pragma unroll
        for (int offc = 32; offc; offc >>= 1) ss += __shfl_down(ss, offc);
        __shared__ float red[4];
        const int wave = threadIdx.x >> 6, lane = threadIdx.x & 63;
        if (lane == 0) red[wave] = ss;
        __syncthreads();
        const float tot = red[0] + red[1] + red[2] + red[3];
        const float sc = rsqrtf(tot / (float)N + 1e-6f);
        if (j < N) {
            ushort4 o;
            o.x = f2b(v[0] * sc * w[j]);
            o.y = f2b(v[1] * sc * w[j + 1]);
            o.z = f2b(v[2] * sc * w[j + 2]);
            o.w = f2b(v[3] * sc * w[j + 3]);
            *(ushort4*)(outp + (size_t)row * N + j) = o;
        }
    } else {
        const int j = threadIdx.x;               // only 0..63 active
        if (j < 64) {
            const int t = row & (T_ - 1);
            const int i = j & 31;
            const float invf = __expf(-LN_BASE_ * (float)(2 * i) * (1.0f / 64.0f));
            const float ang = (float)t * invf;
            const float c = cosf(ang), s = sinf(ang);
            const u16* src = P1 + (size_t)row * 1664 + 1536;
            const float v = b2f(src[j]);
            const float rot = (j < 32) ? -b2f(src[j + 32]) : b2f(src[j - 32]);
            kRb[(size_t)row * 64 + j] = f2b(v * c + rot * s);
        }
    }
}

// ---- fused epilog2: RoPE(q) [2048 blocks] + V^T transpose [2048 blocks] ----
__global__ __launch_bounds__(256) void epilog2_k(const u16* __restrict__ P2,
                                                 u16* __restrict__ qRb,
                                                 const u16* __restrict__ P3,
                                                 u16* __restrict__ Vt) {
    const int bid = blockIdx.x;
    if (bid < 2048) {
        // RoPE for q: rows 2*bid, 2*bid+1; 8xu16 vectorized
        const int row = bid * 2 + (threadIdx.x >> 7);
        const int t = row & (T_ - 1);
        const int e0 = (threadIdx.x & 127) * 8;
        const u16* src = P2 + (size_t)row * 3072 + 2048;
        const int j0 = e0 & 63;
        const ushort4* pv = (const ushort4*)(src + e0);
        const ushort4* pr = (const ushort4*)(src + (j0 < 32 ? e0 + 32 : e0 - 32));
        const float sgn = (j0 < 32) ? -1.f : 1.f;
        ushort4 v01 = pv[0], v23 = pv[1];
        ushort4 r01 = pr[0], r23 = pr[1];
        const u16 vv[8] = {v01.x, v01.y, v01.z, v01.w, v23.x, v23.y, v23.z, v23.w};
        const u16 rr[8] = {r01.x, r01.y, r01.z, r01.w, r23.x, r23.y, r23.z, r23.w};
        u16 o[8];
#pragma unroll
        for (int k = 0; k < 8; ++k) {
            const int i = (j0 + k) & 31;
            const float invf = __expf(-LN_BASE_ * (float)(2 * i) * (1.0f / 64.0f));
            const float ang = (float)t * invf;
            o[k] = f2b(b2f(vv[k]) * cosf(ang) + sgn * b2f(rr[k]) * sinf(ang));
        }
        *(uint4*)(qRb + (size_t)row * 1024 + e0) = *(uint4*)o;
    } else {
        // V^T: P3[:, 2048+c] -> Vt (b, c, T); 64x64 tiles, 16B both sides
        __shared__ u16 tile[64][72];
        const int tt = bid - 2048;
        const int b = tt >> 10;
        const int rem = tt & 1023;
        const int by = rem >> 5, bx = rem & 31;
        const int t0 = by * 64, c0 = bx * 64;
        const int tid = threadIdx.x;
        const int rr2 = tid >> 3;        // 0..31
        const int c8 = tid & 7;          // 16B chunk within 64
#pragma unroll
        for (int p = 0; p < 2; ++p) {
            const int row = p * 32 + rr2;
            *(uint4*)&tile[row][c8 * 8] =
                *(const uint4*)(P3 + (size_t)(b * T_ + t0 + row) * 4096 + 2048 + c0 + c8 * 8);
        }
        __syncthreads();
#pragma unroll
        for (int p = 0; p < 2; ++p) {
            const int c = p * 32 + rr2;
            u16 tmp[8];
#pragma unroll
            for (int j = 0; j < 8; ++j) tmp[j] = tile[c8 * 8 + j][c];
            *(uint4*)(Vt + ((size_t)b * 2048 + c0 + c) * 2048 + t0 + c8 * 8) = *(uint4*)tmp;
        }
    }
}

// ---------------- MFMA flash attention (causal, d=192, dv=128) --------------
// R7-proven structure + R2 changes:
//  (a) sP aliased into sK (dead after QK phase) -> LDS 62.4KB -> 44KB
//      -> 3 blocks/CU. Softmax computed fully into registers, then one
//      barrier, then P stores (extra barrier is covered by +50% occupancy).
//  (b) grid swapped to x=h, y=qb so all 16 qb-blocks of a head share an XCD
//      (linear id % 8 == h % 8) -> K/V panel stays in that XCD's L2.
#define ABQ  128
#define ABK  64
#define KSTR 200   // sK row stride u16
#define VSTR 72    // sV row stride u16
#define PSTR 72    // sP row stride u16
#define QSTRIDE 3072   // P2 row stride (qC cols 0..2047)
#define KSTRIDE 4096   // P3 row stride (kC cols 0..2047)

__global__ __launch_bounds__(256, 3) void attn_mfma_k(
    const u16* __restrict__ qC, const u16* __restrict__ qR,
    const u16* __restrict__ kC, const u16* __restrict__ kR,
    const u16* __restrict__ Vt, u16* __restrict__ outp)
{
    __shared__ __attribute__((aligned(16))) u16 sK[64 * KSTR];    // 25.0 KB (P aliases first 18KB)
    __shared__ __attribute__((aligned(16))) u16 sV[128 * VSTR];   // 18.0 KB

    const int h = blockIdx.x, b = blockIdx.z;                      // swapped grid
    const int qb = b ? (15 - (int)blockIdx.y) : (int)blockIdx.y;   // causal balance
    const int q0 = qb * ABQ;
    const int tid = threadIdx.x, wave = tid >> 6, lane = tid & 63;
    const int r = lane & 15, kq = lane >> 4, r4 = kq * 4;
    const int wq = wave * 32;

    // Q fragments (A-layout) in registers: [mt][kc], k = kc*32 + kq*8 + j
    short8 qf[2][6];
#pragma unroll
    for (int mt = 0; mt < 2; ++mt) {
        const int t = q0 + wq + mt * 16 + r;
        const u16* qcrow = qC + (size_t)(b * T_ + t) * QSTRIDE + h * 128 + kq * 8;
        const u16* qrrow = qR + (size_t)(b * T_ + t) * 1024 + h * 64 + kq * 8;
#pragma unroll
        for (int kc = 0; kc < 4; ++kc) qf[mt][kc] = *(const short8*)(qcrow + kc * 32);
#pragma unroll
        for (int kc = 0; kc < 2; ++kc) qf[mt][4 + kc] = *(const short8*)(qrrow + kc * 32);
    }

    f32x4 Oa[2][8];
#pragma unroll
    for (int mt = 0; mt < 2; ++mt)
#pragma unroll
        for (int nt = 0; nt < 8; ++nt) Oa[mt][nt] = (f32x4){0.f, 0.f, 0.f, 0.f};
    float Lrow[2][4] = {{0.f,0.f,0.f,0.f},{0.f,0.f,0.f,0.f}};

    u16* myP = sK + (size_t)wave * 32 * PSTR;   // alias: P overwrites sK after QK

    const int nkt = 2 * qb + 2;
    for (int kt = 0; kt < nkt; ++kt) {
        const int k0 = kt * ABK;
        // ---- stage K tile: slots s = row*25 + chunk, 25 instr x 1KB
        for (int i = wave; i < 25; i += 4) {
            const int s = i * 64 + lane;
            const int rr = s / 25;
            int cc = s - rr * 25;
            if (cc > 23) cc = 0;                       // pad slot: harmless dup
            const int t = k0 + rr;
            const u16* src = (cc < 16)
                ? kC + (size_t)(b * T_ + t) * KSTRIDE + h * 128 + cc * 8
                : kR + (size_t)(b * T_ + t) * 64 + (cc - 16) * 8;
            __builtin_amdgcn_global_load_lds(
                (const __attribute__((address_space(1))) uint32_t*)(uintptr_t)src,
                (__attribute__((address_space(3))) uint32_t*)(uintptr_t)(sK + i * 512),
                16, 0, 0);
        }
        // ---- stage V^T tile: slots s = dv*9 + chunk, 18 instr
        for (int i = wave; i < 18; i += 4) {
            const int s = i * 64 + lane;
            const int rr = s / 9;
            int cc = s - rr * 9;
            if (cc > 7) cc = 0;                        // pad slot
            const u16* src = Vt + ((size_t)(b * H_ + h) * 128 + rr) * T_ + k0 + cc * 8;
            __builtin_amdgcn_global_load_lds(
                (const __attribute__((address_space(1))) uint32_t*)(uintptr_t)src,
                (__attribute__((address_space(3))) uint32_t*)(uintptr_t)(sV + i * 512),
                16, 0, 0);
        }
        __syncthreads();

        // ---- S = Q K^T  (48 MFMA/wave)
        f32x4 Sa[2][4];
#pragma unroll
        for (int mt = 0; mt < 2; ++mt)
#pragma unroll
            for (int nt = 0; nt < 4; ++nt) Sa[mt][nt] = (f32x4){0.f, 0.f, 0.f, 0.f};
#pragma unroll
        for (int kc = 0; kc < 6; ++kc) {
            short8 kf[4];
#pragma unroll
            for (int nt = 0; nt < 4; ++nt)
                kf[nt] = *(const short8*)&sK[(nt * 16 + r) * KSTR + (kc * 4 + kq) * 8];
#pragma unroll
            for (int mt = 0; mt < 2; ++mt)
#pragma unroll
                for (int nt = 0; nt < 4; ++nt)
                    Sa[mt][nt] = __builtin_amdgcn_mfma_f32_16x16x32_bf16(
                        qf[mt][kc], kf[nt], Sa[mt][nt], 0, 0, 0);
        }

        // ---- no-max softmax into REGISTERS: p = exp2(S*SC2); mask on last 2
        float pv[2][4][4];   // [mt][i][nt]
        if (kt < nkt - 2) {
#pragma unroll
            for (int mt = 0; mt < 2; ++mt)
#pragma unroll
                for (int i = 0; i < 4; ++i) {
                    float sm = 0.f;
#pragma unroll
                    for (int nt = 0; nt < 4; ++nt) {
                        pv[mt][i][nt] = exp2f(Sa[mt][nt][i] * SC2_);
                        sm += pv[mt][i][nt];
                    }
                    Lrow[mt][i] += sm;
                }
        } else {
#pragma unroll
            for (int mt = 0; mt < 2; ++mt)
#pragma unroll
                for (int i = 0; i < 4; ++i) {
                    const int grow = q0 + wq + mt * 16 + r4 + i;
                    float sm = 0.f;
#pragma unroll
                    for (int nt = 0; nt < 4; ++nt) {
                        float pvv = exp2f(Sa[mt][nt][i] * SC2_);
                        pvv = (k0 + nt * 16 + r > grow) ? 0.f : pvv;
                        pv[mt][i][nt] = pvv;
                        sm += pvv;
                    }
                    Lrow[mt][i] += sm;
                }
        }

        // ---- all waves done reading sK -> safe to overwrite with P
        __syncthreads();
#pragma unroll
        for (int mt = 0; mt < 2; ++mt)
#pragma unroll
            for (int i = 0; i < 4; ++i)
#pragma unroll
                for (int nt = 0; nt < 4; ++nt)
                    myP[(mt * 16 + r4 + i) * PSTR + nt * 16 + r] = f2b_fast(pv[mt][i][nt]);

        // ---- O += P V  (P is wave-local; HW lgkmcnt orders write->read)
#pragma unroll
        for (int kc2 = 0; kc2 < 2; ++kc2) {
            short8 pf[2];
#pragma unroll
            for (int mt = 0; mt < 2; ++mt)
                pf[mt] = *(const short8*)&myP[(mt * 16 + r) * PSTR + (kc2 * 4 + kq) * 8];
#pragma unroll
            for (int nt = 0; nt < 8; ++nt) {
                const short8 vf = *(const short8*)&sV[(nt * 16 + r) * VSTR + (kc2 * 4 + kq) * 8];
#pragma unroll
                for (int mt = 0; mt < 2; ++mt)
                    Oa[mt][nt] = __builtin_amdgcn_mfma_f32_16x16x32_bf16(
                        pf[mt], vf, Oa[mt][nt], 0, 0, 0);
            }
        }
        __syncthreads();
    }

    // ---- epilogue: reduce L across the 16 lanes of each quad-group, O /= L
#pragma unroll
    for (int mt = 0; mt < 2; ++mt)
#pragma unroll
        for (int i = 0; i < 4; ++i) {
            float L = Lrow[mt][i];
            L += __shfl_xor(L, 1);
            L += __shfl_xor(L, 2);
            L += __shfl_xor(L, 4);
            L += __shfl_xor(L, 8);
            const float inv = 1.0f / L;
            const int t = q0 + wq + mt * 16 + r4 + i;
            u16* orow = outp + (size_t)(b * T_ + t) * 2048 + h * 128;
#pragma unroll
            for (int nt = 0; nt < 8; ++nt)
                orow[nt * 16 + r] = f2b(Oa[mt][nt][i] * inv);
        }
}

// ---------------- host side -------------------------------------------------
// Workspace plan: 139.46 MB (proven safe; 153 MB OOB'd in round 4).
// U1 time-shared: P1 (phase 1) then attn_out (phase 3). Vt reuses xb.
// 7 dispatches: prep -> proj1 -> normrope -> proj2(pair) -> epilog2 -> attn -> WO
extern "C" void kernel_launch(void* const* d_in, const int* in_sizes, int n_in,
                              void* d_out, int out_size, void* d_ws, size_t ws_size,
                              hipStream_t stream) {
    (void)in_sizes; (void)n_in; (void)out_size; (void)ws_size;
    const float* x     = (const float*)d_in[0];
    const float* W_DQ  = (const float*)d_in[1];
    const float* W_UQ  = (const float*)d_in[2];
    const float* W_QR  = (const float*)d_in[3];
    const float* W_DKV = (const float*)d_in[4];
    const float* W_UK  = (const float*)d_in[5];
    const float* W_UV  = (const float*)d_in[6];
    const float* W_KR  = (const float*)d_in[7];
    const float* W_O   = (const float*)d_in[8];
    const float* qnw   = (const float*)d_in[9];
    const float* kvnw  = (const float*)d_in[10];
    float* out = (float*)d_out;   // fp32 output per reference dtype

    char* base = (char*)d_ws;
    size_t o = 0;
    auto alloc = [&](size_t bytes) {
        char* r = base + o;
        o += (bytes + 255) & ~(size_t)255;
        return r;
    };
    u16* WT1  = (u16*)alloc((size_t)1664 * 2048 * 2);
    u16* WT2  = (u16*)alloc((size_t)3072 * 1024 * 2);
    u16* WT3  = (u16*)alloc((size_t)4096 * 512 * 2);
    u16* WT_O = (u16*)alloc((size_t)2048 * 2048 * 2);
    u16* xb   = (u16*)alloc((size_t)M_ * 2048 * 2);    // x bf16; later Vt
    u16* U1   = (u16*)alloc((size_t)M_ * 2048 * 2);    // P1 then attn_out
    u16* P2   = (u16*)alloc((size_t)M_ * 3072 * 2);    // [qC | qR_raw]
    u16* P3   = (u16*)alloc((size_t)M_ * 4096 * 2);    // [kC | vC]
    u16* cQb  = (u16*)alloc((size_t)M_ * 1024 * 2);
    u16* cKVb = (u16*)alloc((size_t)M_ * 512 * 2);
    u16* qRb  = (u16*)alloc((size_t)M_ * 1024 * 2);
    u16* kRb  = (u16*)alloc((size_t)M_ * 64 * 2);
    u16* P1       = U1;
    u16* attn_out = U1;
    u16* Vt       = xb;

    // ---- dispatch 1: all 8 weight transposes + x cast
    TPack tp;
    const float* srcs[8] = {W_DQ, W_DKV, W_KR, W_UQ, W_QR, W_UK, W_UV, W_O};
    u16* dsts[8] = {WT1, WT1 + (size_t)1024*2048, WT1 + (size_t)1536*2048,
                    WT2, WT2 + (size_t)2048*1024,
                    WT3, WT3 + (size_t)2048*512, WT_O};
    const int Ks[8]   = {2048, 2048, 2048, 1024, 1024, 512, 512, 2048};
    const int Ns[8]   = {1024,  512,   64, 2048, 1024, 2048, 2048, 2048};
    const int ntxs[8] = {  32,   16,    4,   64,   32,   64,   64,   64};
    int cum = 0;
    for (int i = 0; i < 8; ++i) {
        tp.src[i] = srcs[i]; tp.dst[i] = dsts[i];
        tp.K[i] = Ks[i]; tp.N[i] = Ns[i]; tp.ntx[i] = ntxs[i];
        tp.start[i] = cum;
        cum += ntxs[i] * (Ks[i] / 32);
    }
    tp.start[8] = cum;   // 12544 transpose tiles
    const int ncast = (M_ * D_) / 1024;   // 8192 cast blocks
    prep_k<<<cum + ncast, 256, 0, stream>>>(tp, x, xb, cum);

    // ---- dispatch 2: proj1: x @ [W_DQ | W_DKV | W_KR] -> P1 (M x 1664)
    gemm_tn<1><<<dim3(1664/128, M_/128), 256, 0, stream>>>(xb, WT1, (void*)P1, 1664, 2048);

    // ---- dispatch 3: fused rmsnorm(q) + rmsnorm(kv) + rope_k
    normrope_k<<<dim3(M_, 3), 256, 0, stream>>>(P1, qnw, kvnw, cQb, cKVb, kRb);

    // ---- dispatch 4: proj2a (cQ @ [W_UQ|W_QR] -> P2) + proj2b (cKV @ [W_UK|W_UV] -> P3)
    gemm_pair<<<dim3(3072/128 + 4096/128, M_/128), 256, 0, stream>>>(
        cQb,  WT2, P2, 3072, 1024,
        cKVb, WT3, P3, 4096, 512,
        3072/128);

    // ---- dispatch 5: RoPE(q) + V^T transpose
    epilog2_k<<<4096, 256, 0, stream>>>(P2, qRb, P3, Vt);

    // ---- dispatch 6: attention — grid x=h (XCD cluster), y=qb, z=b
    attn_mfma_k<<<dim3(H_, T_/ABQ, B_), 256, 0, stream>>>(P2, qRb, P3, kRb, Vt, attn_out);

    // ---- dispatch 7: output projection -> d_out (fp32)
    gemm_tn<0><<<dim3(2048/128, M_/128), 256, 0, stream>>>(attn_out, WT_O, (void*)out, 2048, 2048);
}

// Round 3
// 414.989 us; speedup vs baseline: 1.3943x; 1.3943x over previous
//
#include <hip/hip_runtime.h>
#include <cstdint>
#include <cstddef>

// ---------------- problem constants ----------------
#define B_   2
#define T_   2048
#define D_   2048
#define H_   16
#define DH_  128
#define DQ_  1024
#define DKV_ 512
#define DR_  64
#define M_   4096            // B_*T_
#define SCALE_ 0.07216878364870323f   // 1/sqrt(DH_+DR_)
#define SC2_   0.10412808709930322f   // SCALE_ * log2(e)
#define LN_BASE_ 13.122363377404328f  // ln(500000)

typedef unsigned short u16;
typedef __attribute__((ext_vector_type(8))) short short8;   // 8 bf16 (4 VGPRs)
typedef __attribute__((ext_vector_type(4))) float f32x4;    // 4 fp32 acc

__device__ __forceinline__ float b2f(u16 u) { return __uint_as_float(((uint32_t)u) << 16); }
__device__ __forceinline__ u16 f2b(float f) {            // RNE
    uint32_t x = __float_as_uint(f);
    return (u16)((x + 0x7fffu + ((x >> 16) & 1u)) >> 16);
}
__device__ __forceinline__ u16 f2b_fast(float f) {       // round-up-ties, 2 ops
    return (u16)((__float_as_uint(f) + 0x8000u) >> 16);
}

__device__ __forceinline__ void gload_lds16(const u16* src, u16* dst) {
    __builtin_amdgcn_global_load_lds(
        (const __attribute__((address_space(1))) uint32_t*)(uintptr_t)src,
        (__attribute__((address_space(3))) uint32_t*)(uintptr_t)dst, 16, 0, 0);
}

// ---- fused prep: 8 weight transposes (+cast) AND x fp32->bf16, one launch ---
struct TPack {
    const float* src[8];
    u16*         dst[8];
    int K[8];      // src rows
    int N[8];      // src cols (real)
    int ntx[8];    // tiles along out-row dim (covers padded N)
    int start[9];  // cumulative tile offsets
};

__global__ __launch_bounds__(256) void prep_k(TPack p, const float* __restrict__ x,
                                              u16* __restrict__ xb, int ntr) {
    const int bid = blockIdx.x;
    if (bid < ntr) {
        __shared__ float tile[32][33];
        int w = 0;
#pragma unroll
        for (int i = 1; i < 8; ++i) if (bid >= p.start[i]) w = i;
        const int lt = bid - p.start[w];
        const int bx = lt % p.ntx[w], by = lt / p.ntx[w];
        const float* in = p.src[w];
        u16* out = p.dst[w];
        const int K = p.K[w], N = p.N[w];
        const int k0 = by * 32, n0 = bx * 32;
        const int tx = threadIdx.x & 31, ty = threadIdx.x >> 5;  // 32x8
#pragma unroll
        for (int i = 0; i < 4; ++i) {
            int k = k0 + ty + i * 8;
            int n = n0 + tx;
            tile[ty + i * 8][tx] = (n < N) ? in[(size_t)k * N + n] : 0.f;
        }
        __syncthreads();
#pragma unroll
        for (int i = 0; i < 4; ++i) {
            int n = n0 + ty + i * 8;     // out row
            out[(size_t)n * K + k0 + tx] = f2b(tile[tx][ty + i * 8]);
        }
    } else {
        const int i = ((bid - ntr) * 256 + threadIdx.x) * 4;
        const float4 v = *(const float4*)(x + i);
        ushort4 o;
        o.x = f2b(v.x); o.y = f2b(v.y); o.z = f2b(v.z); o.w = f2b(v.w);
        *(ushort4*)(xb + i) = o;
    }
}

// ---------------- bf16 GEMM:  C(MxN) = A(MxK) @ B(KxN), Bt given as NxK ------
template <int OUT_BF16>
__global__ __launch_bounds__(256) void gemm_tn(const u16* __restrict__ A,
                                               const u16* __restrict__ Bt,
                                               void* __restrict__ Cv,
                                               int N, int K) {
    __shared__ __attribute__((aligned(16))) u16 lA[128 * 32];
    __shared__ __attribute__((aligned(16))) u16 lB[128 * 32];
    const int m0 = blockIdx.y * 128, n0 = blockIdx.x * 128;
    const int tid = threadIdx.x, wave = tid >> 6, lane = tid & 63;
    const int wm = (wave >> 1) * 64, wn = (wave & 1) * 64;
    const int r = lane & 15, kq = lane >> 4;

    f32x4 acc[4][4];
#pragma unroll
    for (int i = 0; i < 4; ++i)
#pragma unroll
        for (int j = 0; j < 4; ++j) acc[i][j] = (f32x4){0.f, 0.f, 0.f, 0.f};

    for (int kk = 0; kk < K; kk += 32) {
#pragma unroll
        for (int p = 0; p < 2; ++p) {
            const int c = p * 256 + wave * 64 + lane;          // 16B chunk id
            const u16* ga = A  + (size_t)(m0 + (c >> 2)) * K + kk + (c & 3) * 8;
            const u16* gb = Bt + (size_t)(n0 + (c >> 2)) * K + kk + (c & 3) * 8;
            u16* la = lA + (size_t)(p * 256 + wave * 64) * 8;  // wave-uniform base
            u16* lb = lB + (size_t)(p * 256 + wave * 64) * 8;
            __builtin_amdgcn_global_load_lds(
                (const __attribute__((address_space(1))) uint32_t*)(uintptr_t)ga,
                (__attribute__((address_space(3))) uint32_t*)(uintptr_t)la, 16, 0, 0);
            __builtin_amdgcn_global_load_lds(
                (const __attribute__((address_space(1))) uint32_t*)(uintptr_t)gb,
                (__attribute__((address_space(3))) uint32_t*)(uintptr_t)lb, 16, 0, 0);
        }
        __syncthreads();
        short8 av[4], bv[4];
#pragma unroll
        for (int mi = 0; mi < 4; ++mi)
            av[mi] = *(const short8*)&lA[(wm + mi * 16 + r) * 32 + kq * 8];
#pragma unroll
        for (int ni = 0; ni < 4; ++ni)
            bv[ni] = *(const short8*)&lB[(wn + ni * 16 + r) * 32 + kq * 8];
#pragma unroll
        for (int mi = 0; mi < 4; ++mi)
#pragma unroll
            for (int ni = 0; ni < 4; ++ni)
                acc[mi][ni] = __builtin_amdgcn_mfma_f32_16x16x32_bf16(
                    av[mi], bv[ni], acc[mi][ni], 0, 0, 0);
        __syncthreads();
    }
    const int r4 = (lane >> 4) * 4, cc = lane & 15;
#pragma unroll
    for (int mi = 0; mi < 4; ++mi)
#pragma unroll
        for (int ni = 0; ni < 4; ++ni)
#pragma unroll
            for (int i = 0; i < 4; ++i) {
                const int row = m0 + wm + mi * 16 + r4 + i;
                const int col = n0 + wn + ni * 16 + cc;
                const float v = acc[mi][ni][i];
                if (OUT_BF16) ((u16*)Cv)[(size_t)row * N + col] = f2b(v);
                else          ((float*)Cv)[(size_t)row * N + col] = v;
            }
}

// ---- two bf16 GEMMs in ONE launch (block-range routed): both M=4096 --------
__global__ __launch_bounds__(256) void gemm_pair(const u16* __restrict__ A0,
                                                 const u16* __restrict__ B0,
                                                 u16* __restrict__ C0, int N0, int K0,
                                                 const u16* __restrict__ A1,
                                                 const u16* __restrict__ B1,
                                                 u16* __restrict__ C1, int N1, int K1,
                                                 int nx0) {
    __shared__ __attribute__((aligned(16))) u16 lA[128 * 32];
    __shared__ __attribute__((aligned(16))) u16 lB[128 * 32];
    const int sel = (int)blockIdx.x >= nx0;
    const u16* A  = sel ? A1 : A0;
    const u16* Bt = sel ? B1 : B0;
    u16* Cv = sel ? C1 : C0;
    const int N = sel ? N1 : N0, K = sel ? K1 : K0;
    const int bx = sel ? (blockIdx.x - nx0) : blockIdx.x;
    const int m0 = blockIdx.y * 128, n0 = bx * 128;
    const int tid = threadIdx.x, wave = tid >> 6, lane = tid & 63;
    const int wm = (wave >> 1) * 64, wn = (wave & 1) * 64;
    const int r = lane & 15, kq = lane >> 4;

    f32x4 acc[4][4];
#pragma unroll
    for (int i = 0; i < 4; ++i)
#pragma unroll
        for (int j = 0; j < 4; ++j) acc[i][j] = (f32x4){0.f, 0.f, 0.f, 0.f};

    for (int kk = 0; kk < K; kk += 32) {
#pragma unroll
        for (int p = 0; p < 2; ++p) {
            const int c = p * 256 + wave * 64 + lane;
            const u16* ga = A  + (size_t)(m0 + (c >> 2)) * K + kk + (c & 3) * 8;
            const u16* gb = Bt + (size_t)(n0 + (c >> 2)) * K + kk + (c & 3) * 8;
            u16* la = lA + (size_t)(p * 256 + wave * 64) * 8;
            u16* lb = lB + (size_t)(p * 256 + wave * 64) * 8;
            __builtin_amdgcn_global_load_lds(
                (const __attribute__((address_space(1))) uint32_t*)(uintptr_t)ga,
                (__attribute__((address_space(3))) uint32_t*)(uintptr_t)la, 16, 0, 0);
            __builtin_amdgcn_global_load_lds(
                (const __attribute__((address_space(1))) uint32_t*)(uintptr_t)gb,
                (__attribute__((address_space(3))) uint32_t*)(uintptr_t)lb, 16, 0, 0);
        }
        __syncthreads();
        short8 av[4], bv[4];
#pragma unroll
        for (int mi = 0; mi < 4; ++mi)
            av[mi] = *(const short8*)&lA[(wm + mi * 16 + r) * 32 + kq * 8];
#pragma unroll
        for (int ni = 0; ni < 4; ++ni)
            bv[ni] = *(const short8*)&lB[(wn + ni * 16 + r) * 32 + kq * 8];
#pragma unroll
        for (int mi = 0; mi < 4; ++mi)
#pragma unroll
            for (int ni = 0; ni < 4; ++ni)
                acc[mi][ni] = __builtin_amdgcn_mfma_f32_16x16x32_bf16(
                    av[mi], bv[ni], acc[mi][ni], 0, 0, 0);
        __syncthreads();
    }
    const int r4 = (lane >> 4) * 4, cc = lane & 15;
#pragma unroll
    for (int mi = 0; mi < 4; ++mi)
#pragma unroll
        for (int ni = 0; ni < 4; ++ni)
#pragma unroll
            for (int i = 0; i < 4; ++i) {
                const int row = m0 + wm + mi * 16 + r4 + i;
                const int col = n0 + wn + ni * 16 + cc;
                Cv[(size_t)row * N + col] = f2b(acc[mi][ni][i]);
            }
}

// ---- fused per-row ops on P1: rmsnorm(q), rmsnorm(kv), rope_k — one launch --
__global__ __launch_bounds__(256) void normrope_k(const u16* __restrict__ P1,
                                                  const float* __restrict__ qnw,
                                                  const float* __restrict__ kvnw,
                                                  u16* __restrict__ cQb,
                                                  u16* __restrict__ cKVb,
                                                  u16* __restrict__ kRb) {
    const int row = blockIdx.x;
    const int which = blockIdx.y;
    if (which < 2) {
        const int N = which ? 512 : 1024;
        const int off = which ? 1024 : 0;
        const float* w = which ? kvnw : qnw;
        u16* outp = which ? cKVb : cQb;
        const u16* src = P1 + (size_t)row * 1664 + off;
        const int j = threadIdx.x * 4;
        float v[4] = {0.f, 0.f, 0.f, 0.f};
        if (j < N) {
            ushort4 u = *(const ushort4*)(src + j);
            v[0] = b2f(u.x); v[1] = b2f(u.y); v[2] = b2f(u.z); v[3] = b2f(u.w);
        }
        float ss = v[0]*v[0] + v[1]*v[1] + v[2]*v[2] + v[3]*v[3];
#pragma unroll
        for (int offc = 32; offc; offc >>= 1) ss += __shfl_down(ss, offc);
        __shared__ float red[4];
        const int wave = threadIdx.x >> 6, lane = threadIdx.x & 63;
        if (lane == 0) red[wave] = ss;
        __syncthreads();
        const float tot = red[0] + red[1] + red[2] + red[3];
        const float sc = rsqrtf(tot / (float)N + 1e-6f);
        if (j < N) {
            ushort4 o;
            o.x = f2b(v[0] * sc * w[j]);
            o.y = f2b(v[1] * sc * w[j + 1]);
            o.z = f2b(v[2] * sc * w[j + 2]);
            o.w = f2b(v[3] * sc * w[j + 3]);
            *(ushort4*)(outp + (size_t)row * N + j) = o;
        }
    } else {
        const int j = threadIdx.x;               // only 0..63 active
        if (j < 64) {
            const int t = row & (T_ - 1);
            const int i = j & 31;
            const float invf = __expf(-LN_BASE_ * (float)(2 * i) * (1.0f / 64.0f));
            const float ang = (float)t * invf;
            const float c = cosf(ang), s = sinf(ang);
            const u16* src = P1 + (size_t)row * 1664 + 1536;
            const float v = b2f(src[j]);
            const float rot = (j < 32) ? -b2f(src[j + 32]) : b2f(src[j - 32]);
            kRb[(size_t)row * 64 + j] = f2b(v * c + rot * s);
        }
    }
}

// ---- fused epilog2: RoPE(q) [2048 blocks] + V^T transpose [2048 blocks] ----
__global__ __launch_bounds__(256) void epilog2_k(const u16* __restrict__ P2,
                                                 u16* __restrict__ qRb,
                                                 const u16* __restrict__ P3,
                                                 u16* __restrict__ Vt) {
    const int bid = blockIdx.x;
    if (bid < 2048) {
        // RoPE for q: rows 2*bid, 2*bid+1; 8xu16 vectorized
        const int row = bid * 2 + (threadIdx.x >> 7);
        const int t = row & (T_ - 1);
        const int e0 = (threadIdx.x & 127) * 8;
        const u16* src = P2 + (size_t)row * 3072 + 2048;
        const int j0 = e0 & 63;
        const ushort4* pv = (const ushort4*)(src + e0);
        const ushort4* pr = (const ushort4*)(src + (j0 < 32 ? e0 + 32 : e0 - 32));
        const float sgn = (j0 < 32) ? -1.f : 1.f;
        ushort4 v01 = pv[0], v23 = pv[1];
        ushort4 r01 = pr[0], r23 = pr[1];
        const u16 vv[8] = {v01.x, v01.y, v01.z, v01.w, v23.x, v23.y, v23.z, v23.w};
        const u16 rr[8] = {r01.x, r01.y, r01.z, r01.w, r23.x, r23.y, r23.z, r23.w};
        u16 o[8];
#pragma unroll
        for (int k = 0; k < 8; ++k) {
            const int i = (j0 + k) & 31;
            const float invf = __expf(-LN_BASE_ * (float)(2 * i) * (1.0f / 64.0f));
            const float ang = (float)t * invf;
            o[k] = f2b(b2f(vv[k]) * cosf(ang) + sgn * b2f(rr[k]) * sinf(ang));
        }
        *(uint4*)(qRb + (size_t)row * 1024 + e0) = *(uint4*)o;
    } else {
        // V^T: P3[:, 2048+c] -> Vt (b, c, T); 64x64 tiles, 16B both sides
        __shared__ u16 tile[64][72];
        const int tt = bid - 2048;
        const int b = tt >> 10;
        const int rem = tt & 1023;
        const int by = rem >> 5, bx = rem & 31;
        const int t0 = by * 64, c0 = bx * 64;
        const int tid = threadIdx.x;
        const int rr2 = tid >> 3;        // 0..31
        const int c8 = tid & 7;          // 16B chunk within 64
#pragma unroll
        for (int p = 0; p < 2; ++p) {
            const int row = p * 32 + rr2;
            *(uint4*)&tile[row][c8 * 8] =
                *(const uint4*)(P3 + (size_t)(b * T_ + t0 + row) * 4096 + 2048 + c0 + c8 * 8);
        }
        __syncthreads();
#pragma unroll
        for (int p = 0; p < 2; ++p) {
            const int c = p * 32 + rr2;
            u16 tmp[8];
#pragma unroll
            for (int j = 0; j < 8; ++j) tmp[j] = tile[c8 * 8 + j][c];
            *(uint4*)(Vt + ((size_t)b * 2048 + c0 + c) * 2048 + t0 + c8 * 8) = *(uint4*)tmp;
        }
    }
}

// ---------------- MFMA flash attention (causal, d=192, dv=128) --------------
// R3: T3/T4 pipelined restructure.
//  - 512 thr = 8 waves x 16 q-rows (ABQ=128 unchanged; per-block work identical)
//  - combined K|V LDS tile, DOUBLE-buffered (2 x 43KB) + sP 18KB = 104 KB
//    -> 1 block/CU, 8 waves = 2 waves/SIMD (MFMA/VALU overlap preserved)
//  - staging: exactly 6 global_load_lds per wave (48 padded slots);
//    main loop: STAGE(t+1) -> s_waitcnt vmcnt(6) -> raw s_barrier -> compute(t)
//    -> raw s_barrier.  NO __syncthreads => no vmcnt(0) drain; tile t+1 loads
//    stay in flight under tile t compute (T3/T4, m218-verified pattern).
//  - no-max softmax identical to R1 (P direct to wave-local sP, no reg P array)
#define ABQ  128
#define ABK  64
#define NW   8
#define KSTR 200   // sK row stride u16 (25 chunks x 8)
#define VSTR 72    // sV row stride u16 (9 chunks x 8)
#define PSTR 72    // sP row stride u16
#define VOFF 12800 // u16 offset of V region inside a KV buffer (25*512)
#define KVSZ 22016 // u16 per KV buffer (43*512)
#define QSTRIDE 3072   // P2 row stride (qC cols 0..2047)
#define KSTRIDE 4096   // P3 row stride (kC cols 0..2047)

__global__ __launch_bounds__(512, 1) void attn_mfma_k(
    const u16* __restrict__ qC, const u16* __restrict__ qR,
    const u16* __restrict__ kC, const u16* __restrict__ kR,
    const u16* __restrict__ Vt, u16* __restrict__ outp)
{
    __shared__ __attribute__((aligned(16))) u16 sKV[2][KVSZ];   // 2 x 43 KB
    __shared__ __attribute__((aligned(16))) u16 sP[NW * 16 * PSTR]; // 18 KB

    const int h = blockIdx.x, b = blockIdx.z;                      // x=h: XCD cluster
    const int qb = b ? (15 - (int)blockIdx.y) : (int)blockIdx.y;   // causal balance
    const int q0 = qb * ABQ;
    const int tid = threadIdx.x, wave = tid >> 6, lane = tid & 63;
    const int r = lane & 15, kq = lane >> 4, r4 = kq * 4;
    const int wq = wave * 16;

    // ---- per-wave staging plan: 6 slots each, precomputed bases
    const u16* gsrc[6]; int gstep[6]; int doff[6];
#pragma unroll
    for (int j = 0; j < 6; ++j) {
        const int i = wave + NW * j;              // 0..47
        const int slot = (i < 43) ? i : (i - 43); // pad slots dup K slots 0..4
        if (slot < 25) {                          // K chunk
            const int s = slot * 64 + lane;
            const int rr2 = s / 25;
            int cc = s - rr2 * 25;
            if (cc > 23) cc = 0;                  // pad col: harmless dup
            if (cc < 16) {
                gsrc[j] = kC + (size_t)(b * T_ + rr2) * KSTRIDE + h * 128 + cc * 8;
                gstep[j] = ABK * KSTRIDE;
            } else {
                gsrc[j] = kR + (size_t)(b * T_ + rr2) * 64 + (cc - 16) * 8;
                gstep[j] = ABK * 64;
            }
            doff[j] = slot * 512;
        } else {                                  // V chunk
            const int sl = slot - 25;             // 0..17
            const int s = sl * 64 + lane;
            const int rr2 = s / 9;
            int cc = s - rr2 * 9;
            if (cc > 7) cc = 0;                   // pad col
            gsrc[j] = Vt + ((size_t)(b * H_ + h) * 128 + rr2) * T_ + cc * 8;
            gstep[j] = ABK;
            doff[j] = VOFF + sl * 512;
        }
    }

    // ---- Q fragments (A-layout) in registers: rows q0+wq+r
    short8 qf[6];
    {
        const int t = q0 + wq + r;
        const u16* qcrow = qC + (size_t)(b * T_ + t) * QSTRIDE + h * 128 + kq * 8;
        const u16* qrrow = qR + (size_t)(b * T_ + t) * 1024 + h * 64 + kq * 8;
#pragma unroll
        for (int kc = 0; kc < 4; ++kc) qf[kc] = *(const short8*)(qcrow + kc * 32);
#pragma unroll
        for (int kc = 0; kc < 2; ++kc) qf[4 + kc] = *(const short8*)(qrrow + kc * 32);
    }

    f32x4 Oa[8];
#pragma unroll
    for (int nt = 0; nt < 8; ++nt) Oa[nt] = (f32x4){0.f, 0.f, 0.f, 0.f};
    float Lrow[4] = {0.f, 0.f, 0.f, 0.f};

    u16* myP = sP + wave * 16 * PSTR;

    auto STAGE = [&](int kt2, int bs) {
        u16* dst = &sKV[bs][0];
#pragma unroll
        for (int j = 0; j < 6; ++j)
            gload_lds16(gsrc[j] + (size_t)kt2 * (size_t)gstep[j], dst + doff[j]);
    };

    const int nkt = 2 * qb + 2;
    STAGE(0, 0);
    for (int kt = 0; kt < nkt; ++kt) {
        const int cur = kt & 1;
        if (kt + 1 < nkt) STAGE(kt + 1, cur ^ 1);
        // acquire: own tile-kt loads (6 oldest) complete; barrier makes it
        // block-wide. kt==0 also drains Q loads; last iter has no prefetch.
        if (kt == 0 || kt + 1 >= nkt) {
            asm volatile("s_waitcnt vmcnt(0)" ::: "memory");
        } else {
            asm volatile("s_waitcnt vmcnt(6)" ::: "memory");
        }
        __builtin_amdgcn_s_barrier();
        asm volatile("" ::: "memory");

        const u16* cK = &sKV[cur][0];
        const u16* cV = &sKV[cur][VOFF];
        const int k0 = kt * ABK;

        // ---- S = Q K^T  (24 MFMA/wave)
        f32x4 Sa[4];
#pragma unroll
        for (int nt = 0; nt < 4; ++nt) Sa[nt] = (f32x4){0.f, 0.f, 0.f, 0.f};
#pragma unroll
        for (int kc = 0; kc < 6; ++kc) {
            short8 kf[4];
#pragma unroll
            for (int nt = 0; nt < 4; ++nt)
                kf[nt] = *(const short8*)&cK[(nt * 16 + r) * KSTR + (kc * 4 + kq) * 8];
#pragma unroll
            for (int nt = 0; nt < 4; ++nt)
                Sa[nt] = __builtin_amdgcn_mfma_f32_16x16x32_bf16(
                    qf[kc], kf[nt], Sa[nt], 0, 0, 0);
        }

        // ---- no-max softmax: p = exp2(S*SC2); wave-uniform mask split
        if (kt < nkt - 2) {
#pragma unroll
            for (int i = 0; i < 4; ++i) {
                float sm = 0.f;
#pragma unroll
                for (int nt = 0; nt < 4; ++nt) {
                    const float p = exp2f(Sa[nt][i] * SC2_);
                    sm += p;
                    myP[(r4 + i) * PSTR + nt * 16 + r] = f2b_fast(p);
                }
                Lrow[i] += sm;
            }
        } else {
#pragma unroll
            for (int i = 0; i < 4; ++i) {
                const int grow = q0 + wq + r4 + i;
                float sm = 0.f;
#pragma unroll
                for (int nt = 0; nt < 4; ++nt) {
                    float p = exp2f(Sa[nt][i] * SC2_);
                    p = (k0 + nt * 16 + r > grow) ? 0.f : p;
                    sm += p;
                    myP[(r4 + i) * PSTR + nt * 16 + r] = f2b_fast(p);
                }
                Lrow[i] += sm;
            }
        }

        // ---- O += P V  (P wave-local; same-wave DS order via lgkmcnt)
#pragma unroll
        for (int kc2 = 0; kc2 < 2; ++kc2) {
            const short8 pf = *(const short8*)&myP[r * PSTR + (kc2 * 4 + kq) * 8];
#pragma unroll
            for (int nt = 0; nt < 8; ++nt) {
                const short8 vf = *(const short8*)&cV[(nt * 16 + r) * VSTR + (kc2 * 4 + kq) * 8];
                Oa[nt] = __builtin_amdgcn_mfma_f32_16x16x32_bf16(
                    pf, vf, Oa[nt], 0, 0, 0);
            }
        }

        // release: all waves done reading buf[cur] before kt+1 stages into it
        asm volatile("" ::: "memory");
        __builtin_amdgcn_s_barrier();
        asm volatile("" ::: "memory");
    }

    // ---- epilogue: reduce L across the 16 lanes of each quad-group, O /= L
#pragma unroll
    for (int i = 0; i < 4; ++i) {
        float L = Lrow[i];
        L += __shfl_xor(L, 1);
        L += __shfl_xor(L, 2);
        L += __shfl_xor(L, 4);
        L += __shfl_xor(L, 8);
        const float inv = 1.0f / L;
        const int t = q0 + wq + r4 + i;
        u16* orow = outp + (size_t)(b * T_ + t) * 2048 + h * 128;
#pragma unroll
        for (int nt = 0; nt < 8; ++nt)
            orow[nt * 16 + r] = f2b(Oa[nt][i] * inv);
    }
}

// ---------------- host side -------------------------------------------------
// Workspace plan: 139.46 MB (proven safe; 153 MB OOB'd in round 4).
// U1 time-shared: P1 (phase 1) then attn_out (phase 3). Vt reuses xb.
// 7 dispatches: prep -> proj1 -> normrope -> proj2(pair) -> epilog2 -> attn -> WO
extern "C" void kernel_launch(void* const* d_in, const int* in_sizes, int n_in,
                              void* d_out, int out_size, void* d_ws, size_t ws_size,
                              hipStream_t stream) {
    (void)in_sizes; (void)n_in; (void)out_size; (void)ws_size;
    const float* x     = (const float*)d_in[0];
    const float* W_DQ  = (const float*)d_in[1];
    const float* W_UQ  = (const float*)d_in[2];
    const float* W_QR  = (const float*)d_in[3];
    const float* W_DKV = (const float*)d_in[4];
    const float* W_UK  = (const float*)d_in[5];
    const float* W_UV  = (const float*)d_in[6];
    const float* W_KR  = (const float*)d_in[7];
    const float* W_O   = (const float*)d_in[8];
    const float* qnw   = (const float*)d_in[9];
    const float* kvnw  = (const float*)d_in[10];
    float* out = (float*)d_out;   // fp32 output per reference dtype

    char* base = (char*)d_ws;
    size_t o = 0;
    auto alloc = [&](size_t bytes) {
        char* r = base + o;
        o += (bytes + 255) & ~(size_t)255;
        return r;
    };
    u16* WT1  = (u16*)alloc((size_t)1664 * 2048 * 2);
    u16* WT2  = (u16*)alloc((size_t)3072 * 1024 * 2);
    u16* WT3  = (u16*)alloc((size_t)4096 * 512 * 2);
    u16* WT_O = (u16*)alloc((size_t)2048 * 2048 * 2);
    u16* xb   = (u16*)alloc((size_t)M_ * 2048 * 2);    // x bf16; later Vt
    u16* U1   = (u16*)alloc((size_t)M_ * 2048 * 2);    // P1 then attn_out
    u16* P2   = (u16*)alloc((size_t)M_ * 3072 * 2);    // [qC | qR_raw]
    u16* P3   = (u16*)alloc((size_t)M_ * 4096 * 2);    // [kC | vC]
    u16* cQb  = (u16*)alloc((size_t)M_ * 1024 * 2);
    u16* cKVb = (u16*)alloc((size_t)M_ * 512 * 2);
    u16* qRb  = (u16*)alloc((size_t)M_ * 1024 * 2);
    u16* kRb  = (u16*)alloc((size_t)M_ * 64 * 2);
    u16* P1       = U1;
    u16* attn_out = U1;
    u16* Vt       = xb;

    // ---- dispatch 1: all 8 weight transposes + x cast
    TPack tp;
    const float* srcs[8] = {W_DQ, W_DKV, W_KR, W_UQ, W_QR, W_UK, W_UV, W_O};
    u16* dsts[8] = {WT1, WT1 + (size_t)1024*2048, WT1 + (size_t)1536*2048,
                    WT2, WT2 + (size_t)2048*1024,
                    WT3, WT3 + (size_t)2048*512, WT_O};
    const int Ks[8]   = {2048, 2048, 2048, 1024, 1024, 512, 512, 2048};
    const int Ns[8]   = {1024,  512,   64, 2048, 1024, 2048, 2048, 2048};
    const int ntxs[8] = {  32,   16,    4,   64,   32,   64,   64,   64};
    int cum = 0;
    for (int i = 0; i < 8; ++i) {
        tp.src[i] = srcs[i]; tp.dst[i] = dsts[i];
        tp.K[i] = Ks[i]; tp.N[i] = Ns[i]; tp.ntx[i] = ntxs[i];
        tp.start[i] = cum;
        cum += ntxs[i] * (Ks[i] / 32);
    }
    tp.start[8] = cum;   // 12544 transpose tiles
    const int ncast = (M_ * D_) / 1024;   // 8192 cast blocks
    prep_k<<<cum + ncast, 256, 0, stream>>>(tp, x, xb, cum);

    // ---- dispatch 2: proj1: x @ [W_DQ | W_DKV | W_KR] -> P1 (M x 1664)
    gemm_tn<1><<<dim3(1664/128, M_/128), 256, 0, stream>>>(xb, WT1, (void*)P1, 1664, 2048);

    // ---- dispatch 3: fused rmsnorm(q) + rmsnorm(kv) + rope_k
    normrope_k<<<dim3(M_, 3), 256, 0, stream>>>(P1, qnw, kvnw, cQb, cKVb, kRb);

    // ---- dispatch 4: proj2a (cQ @ [W_UQ|W_QR] -> P2) + proj2b (cKV @ [W_UK|W_UV] -> P3)
    gemm_pair<<<dim3(3072/128 + 4096/128, M_/128), 256, 0, stream>>>(
        cQb,  WT2, P2, 3072, 1024,
        cKVb, WT3, P3, 4096, 512,
        3072/128);

    // ---- dispatch 5: RoPE(q) + V^T transpose
    epilog2_k<<<4096, 256, 0, stream>>>(P2, qRb, P3, Vt);

    // ---- dispatch 6: attention — 512 thr/block; grid x=h (XCD), y=qb, z=b
    attn_mfma_k<<<dim3(H_, T_/ABQ, B_), 512, 0, stream>>>(P2, qRb, P3, kRb, Vt, attn_out);

    // ---- dispatch 7: output projection -> d_out (fp32)
    gemm_tn<0><<<dim3(2048/128, M_/128), 256, 0, stream>>>(attn_out, WT_O, (void*)out, 2048, 2048);
}